// Round 4
// baseline (543.727 us; speedup 1.0000x reference)
//
#include <hip/hip_runtime.h>
#include <math.h>

#define D 512
#define AS1 __attribute__((address_space(1)))
#define AS3 __attribute__((address_space(3)))

typedef _Float16 f16x8 __attribute__((ext_vector_type(8)));
typedef float f32x4 __attribute__((ext_vector_type(4)));

// ---------------- Transpose: zTb[g][d][kk_swz] = fp16(h[g*32+k][d]) ----------------
__global__ __launch_bounds__(256) void transpose_kernel(
    const float* __restrict__ h, _Float16* __restrict__ zTb, int N)
{
    __shared__ float tile[64][65];
    const int t0 = blockIdx.x * 64;
    const int d0 = blockIdx.y * 64;
    const int tid = threadIdx.x;
    const int r0 = tid >> 4;
    const int c0 = (tid & 15) * 4;
    #pragma unroll
    for (int k = 0; k < 4; k++) {
        int r = r0 + k * 16;
        float4 v = *(const float4*)(h + (size_t)(t0 + r) * D + d0 + c0);
        tile[r][c0] = v.x; tile[r][c0+1] = v.y; tile[r][c0+2] = v.z; tile[r][c0+3] = v.w;
    }
    __syncthreads();
    const int g = (t0 >> 5) + (c0 >> 5);
    const int kk = c0 & 31;
    const int kg = kk >> 3;
    const int sub = kk & 7;
    #pragma unroll
    for (int k = 0; k < 4; k++) {
        int dd = d0 + r0 + k * 16;
        int kks = ((kg + (dd >> 1)) & 3) * 8 + sub;
        union { _Float16 hh[4]; uint2 u2; } pk;
        #pragma unroll
        for (int i = 0; i < 4; i++) pk.hh[i] = (_Float16)tile[c0 + i][r0 + k * 16];
        *(uint2*)(zTb + (size_t)g * 16384 + dd * 32 + kks) = pk.u2;
    }
}

// ---------------- Linear via fp16 MFMA: x16 = fp16(h @ W^T + b) ----------------
__global__ __launch_bounds__(256) void linear_mfma(
    const float* __restrict__ h, const float* __restrict__ W,
    const float* __restrict__ bias, _Float16* __restrict__ x16, int N)
{
    __shared__ _Float16 sA[128 * 72];
    __shared__ _Float16 sB[128 * 72];
    const int tid  = threadIdx.x;
    const int m0 = blockIdx.x * 128;
    const int n0 = blockIdx.y * 128;
    const int wave = tid >> 6, lane = tid & 63;
    const int l15 = lane & 15, quad = lane >> 4;
    const int wm = (wave >> 1) * 64, wn = (wave & 1) * 64;

    f32x4 acc[4][4];
    #pragma unroll
    for (int mi = 0; mi < 4; mi++)
        #pragma unroll
        for (int ni = 0; ni < 4; ni++) acc[mi][ni] = (f32x4){0.f,0.f,0.f,0.f};

    for (int k0 = 0; k0 < D; k0 += 64) {
        __syncthreads();
        #pragma unroll
        for (int i = 0; i < 8; i++) {
            int idx = tid + 256 * i;
            int row = idx >> 4;
            int c4  = (idx & 15) * 4;
            float4 va = *(const float4*)(h + (size_t)(m0 + row) * D + k0 + c4);
            float4 vb = *(const float4*)(W + (size_t)(n0 + row) * D + k0 + c4);
            union { _Float16 hh[4]; uint2 u2; } pa, pb;
            pa.hh[0] = (_Float16)va.x; pa.hh[1] = (_Float16)va.y;
            pa.hh[2] = (_Float16)va.z; pa.hh[3] = (_Float16)va.w;
            pb.hh[0] = (_Float16)vb.x; pb.hh[1] = (_Float16)vb.y;
            pb.hh[2] = (_Float16)vb.z; pb.hh[3] = (_Float16)vb.w;
            *(uint2*)(sA + row * 72 + c4) = pa.u2;
            *(uint2*)(sB + row * 72 + c4) = pb.u2;
        }
        __syncthreads();
        #pragma unroll
        for (int kc = 0; kc < 2; kc++) {
            f16x8 a[4], b[4];
            #pragma unroll
            for (int mi = 0; mi < 4; mi++)
                a[mi] = *(const f16x8*)(sA + (wm + mi*16 + l15)*72 + kc*32 + quad*8);
            #pragma unroll
            for (int ni = 0; ni < 4; ni++)
                b[ni] = *(const f16x8*)(sB + (wn + ni*16 + l15)*72 + kc*32 + quad*8);
            #pragma unroll
            for (int mi = 0; mi < 4; mi++)
                #pragma unroll
                for (int ni = 0; ni < 4; ni++)
                    acc[mi][ni] = __builtin_amdgcn_mfma_f32_16x16x32_f16(a[mi], b[ni], acc[mi][ni], 0, 0, 0);
        }
    }
    float bv[4];
    #pragma unroll
    for (int ni = 0; ni < 4; ni++) bv[ni] = bias[n0 + wn + ni*16 + l15];
    #pragma unroll
    for (int mi = 0; mi < 4; mi++)
        #pragma unroll
        for (int ni = 0; ni < 4; ni++)
            #pragma unroll
            for (int r = 0; r < 4; r++) {
                int row = m0 + wm + mi*16 + quad*4 + r;
                x16[(size_t)row * D + n0 + wn + ni*16 + l15] = (_Float16)(acc[mi][ni][r] + bv[ni]);
            }
}

// ---------------- Flash attention v10: producer-consumer role split -------------
// LDS-BW-bound fix (r3 post-mortem): kill the 4x read redundancy.
//  QBLK=128, 12 waves: waves 0-3 = score waves (32q each, Qf=128 regs, each
//  ybuf B-frag reused for 2 q-subtiles); waves 4-11 = PV waves (32q x 256d,
//  O=128 regs, each zbuf B-frag reused for 2 q-subtiles, dims split 2 ways).
//  Per-CU LDS traffic per 128q: 1312KB -> ~370KB (3.5x).
//  Qf and O overlay in one 128-reg array (bit_cast) -- roles never need both.
//  Pipeline (PV lags scores by 1 k-block; P/al double-buffered; z double-buffered):
//   A(kb): [PVw] issue z(kb)->zbuf[kb&1]; rescale O by al(kb-1); PV(kb-1) d-tiles 0-7
//          [Sw]  S-MFMAs(kb) from ybuf
//   BAR1
//   B(kb): [PVw] issue y(kb+1)->ybuf; PV(kb-1) d-tiles 8-15
//          [Sw]  softmax(kb), write P->pbuf[kb&1], al->albuf[kb&1]
//   BAR2
__global__ __launch_bounds__(768, 3) void attn10_kernel(
    const float* __restrict__ h, const _Float16* __restrict__ x16,
    const _Float16* __restrict__ zTb, const int* __restrict__ lens,
    float* __restrict__ out, int N, int B)
{
    // ybuf  [32][520]            @ 0       (33,280 B)
    // zbuf  2 x [512][32] swz    @ 33,280  (65,536 B)
    // pbuf  2 x [8][16][40]      @ 98,816  (20,480 B)
    // albuf 2 x float[128]       @ 119,296 ( 1,024 B)
    // lbuf  float[128]           @ 120,320 (   512 B)
    __shared__ __align__(16) unsigned char smem[120832];
    _Float16* ybuf = (_Float16*)smem;

    const int is64 = (lens[1] == 0 && lens[3] == 0) ? 1 : 0;

    int seg = -1, tile = 0;
    if (B == 16) {
        // XCD-affine: xcd owns segments (15-xcd, xcd); all pairs = 24 tiles of 128q.
        const int xcd = blockIdx.x & 7;
        const int idx = blockIdx.x >> 3;
        const int sL = 15 - xcd, sS = xcd;
        const int LL = is64 ? lens[2 * sL] : lens[sL];
        const int LS = is64 ? lens[2 * sS] : lens[sS];
        const int ntL = (LL + 127) >> 7;
        const int ntS = (LS + 127) >> 7;
        if (idx < ntL)            { seg = sL; tile = idx; }
        else if (idx < ntL + ntS) { seg = sS; tile = idx - ntL; }
        else return;
    } else {
        int blk = blockIdx.x;
        int acc = 0;
        for (int t = 0; t < B; t++) {
            int s = B - 1 - t;
            int Ls = is64 ? lens[2 * s] : lens[s];
            int nt = (Ls + 127) >> 7;
            if (seg < 0 && blk < acc + nt) { seg = s; tile = blk - acc; }
            acc += nt;
        }
        if (seg < 0) return;
    }
    int off = 0;
    for (int t = 0; t < seg; t++) off += is64 ? lens[2 * t] : lens[t];
    const int len = is64 ? lens[2 * seg] : lens[seg];

    const int tid  = threadIdx.x;
    const int wv   = tid >> 6;          // 0..3 score waves, 4..11 PV waves
    const int lane = tid & 63;
    const int l15  = lane & 15;
    const int quad = lane >> 4;
    const int zcol = ((quad + (l15 >> 1)) & 3) * 8;
    const int nkb  = (len + 31) >> 5;

    const bool isS = (wv < 4);
    const int sw = wv;                  // score wave id (0..3)
    const int pw = wv - 4;              // PV wave id (0..7)
    const int qt = pw & 3;              // PV query 32-group
    const int dg = pw >> 2;             // PV dim half (0/1)

    // 128-reg overlay: score waves use it as Qf[2][16] f16x8; PV waves as O[2][16] f32x4
    f32x4 big[2][16];
    float mR[2][4], lR[2][4];
    #pragma unroll
    for (int a = 0; a < 2; a++)
        #pragma unroll
        for (int b = 0; b < 16; b++) big[a][b] = (f32x4){0.f,0.f,0.f,0.f};
    #pragma unroll
    for (int a = 0; a < 2; a++)
        #pragma unroll
        for (int r = 0; r < 4; r++) { mR[a][r] = -1e30f; lR[a][r] = 0.f; }

    if (isS) {
        // Qf load: 2 q-subtiles x 16 chunks from h (raw z side = queries)
        #pragma unroll
        for (int qs = 0; qs < 2; qs++) {
            int qr = off + tile * 128 + sw * 32 + qs * 16 + l15;
            if (qr > N - 1) qr = N - 1;
            const float* hr = h + (size_t)qr * D;
            #pragma unroll
            for (int c = 0; c < 16; c++) {
                float4 u = *(const float4*)(hr + c * 32 + quad * 8);
                float4 v = *(const float4*)(hr + c * 32 + quad * 8 + 4);
                f16x8 q;
                q[0] = (_Float16)u.x; q[1] = (_Float16)u.y; q[2] = (_Float16)u.z; q[3] = (_Float16)u.w;
                q[4] = (_Float16)v.x; q[5] = (_Float16)v.y; q[6] = (_Float16)v.z; q[7] = (_Float16)v.w;
                big[qs][c] = __builtin_bit_cast(f32x4, q);
            }
        }
    } else {
        // prologue: stage y(0), 4 rows per PV wave
        #pragma unroll
        for (int i = 0; i < 4; i++) {
            int r = pw * 4 + i;
            int gr = off + r; if (gr > N - 1) gr = N - 1;
            const _Float16* gsrc = x16 + (size_t)gr * D + lane * 8;
            __builtin_amdgcn_global_load_lds((const AS1 unsigned int*)gsrc,
                                             (AS3 unsigned int*)(ybuf + r * 520), 16, 0, 0);
        }
    }
    __syncthreads();   // y(0) resident

    for (int kb = 0; kb <= nkb; kb++) {
        const int par = (kb - 1) & 1;
        f32x4 s[2][2];

        // ================= Phase A =================
        if (!isS) {
            if (kb < nkb) {
                // issue z(kb) -> zbuf[kb&1]: 4 x 1KB chunks per PV wave
                const _Float16* zsrc = zTb + (size_t)((off + kb * 32) >> 5) * 16384;
                _Float16* zdst = (_Float16*)(smem + 33280 + (kb & 1) * 32768);
                #pragma unroll
                for (int i = 0; i < 4; i++) {
                    int co = (pw * 4 + i) * 512 + lane * 8;
                    __builtin_amdgcn_global_load_lds((const AS1 unsigned int*)(zsrc + co),
                                                     (AS3 unsigned int*)(zdst + co), 16, 0, 0);
                }
            }
            if (kb >= 1) {
                const float* alr = (const float*)(smem + 119296 + par * 512);
                f32x4 av0 = *(const f32x4*)(alr + (qt * 2 + 0) * 16 + quad * 4);
                f32x4 av1 = *(const f32x4*)(alr + (qt * 2 + 1) * 16 + quad * 4);
                bool upd = false;
                #pragma unroll
                for (int r = 0; r < 4; r++) upd |= (av0[r] != 1.0f) | (av1[r] != 1.0f);
                if (__ballot(upd)) {
                    #pragma unroll
                    for (int f = 0; f < 16; f++) { big[0][f] *= av0; big[1][f] *= av1; }
                }
                const _Float16* pb = (const _Float16*)(smem + 98816 + par * 10240);
                f16x8 pa0 = *(const f16x8*)(pb + (qt * 2 + 0) * 640 + l15 * 40 + quad * 8);
                f16x8 pa1 = *(const f16x8*)(pb + (qt * 2 + 1) * 640 + l15 * 40 + quad * 8);
                const _Float16* zb = (const _Float16*)(smem + 33280 + par * 32768);
                __builtin_amdgcn_s_setprio(1);
                #pragma unroll
                for (int f = 0; f < 8; f++) {
                    f16x8 zf = *(const f16x8*)(zb + ((dg * 16 + f) * 16 + l15) * 32 + zcol);
                    big[0][f] = __builtin_amdgcn_mfma_f32_16x16x32_f16(pa0, zf, big[0][f], 0, 0, 0);
                    big[1][f] = __builtin_amdgcn_mfma_f32_16x16x32_f16(pa1, zf, big[1][f], 0, 0, 0);
                }
                __builtin_amdgcn_s_setprio(0);
            }
        } else if (kb < nkb) {
            // scores: 32q x 32k, each B-frag reused for both q-subtiles
            #pragma unroll
            for (int qs = 0; qs < 2; qs++)
                #pragma unroll
                for (int kh = 0; kh < 2; kh++) s[qs][kh] = (f32x4){0.f,0.f,0.f,0.f};
            __builtin_amdgcn_s_setprio(1);
            #pragma unroll
            for (int c = 0; c < 16; c++) {
                f16x8 b0 = *(const f16x8*)(ybuf + l15 * 520 + c * 32 + quad * 8);
                f16x8 b1 = *(const f16x8*)(ybuf + (16 + l15) * 520 + c * 32 + quad * 8);
                f16x8 a0 = __builtin_bit_cast(f16x8, big[0][c]);
                f16x8 a1 = __builtin_bit_cast(f16x8, big[1][c]);
                s[0][0] = __builtin_amdgcn_mfma_f32_16x16x32_f16(a0, b0, s[0][0], 0, 0, 0);
                s[0][1] = __builtin_amdgcn_mfma_f32_16x16x32_f16(a0, b1, s[0][1], 0, 0, 0);
                s[1][0] = __builtin_amdgcn_mfma_f32_16x16x32_f16(a1, b0, s[1][0], 0, 0, 0);
                s[1][1] = __builtin_amdgcn_mfma_f32_16x16x32_f16(a1, b1, s[1][1], 0, 0, 0);
            }
            __builtin_amdgcn_s_setprio(0);
            const int kk0 = kb * 32 + l15, kk1 = kb * 32 + 16 + l15;
            #pragma unroll
            for (int qs = 0; qs < 2; qs++)
                #pragma unroll
                for (int r = 0; r < 4; r++) {
                    if (kk0 >= len) s[qs][0][r] = -1e30f;
                    if (kk1 >= len) s[qs][1][r] = -1e30f;
                }
        }

        __syncthreads();   // BAR1

        // ================= Phase B =================
        if (!isS) {
            if (kb + 1 < nkb) {
                const int jn = (kb + 1) * 32;
                #pragma unroll
                for (int i = 0; i < 4; i++) {
                    int r = pw * 4 + i;
                    int gr = off + jn + r; if (gr > N - 1) gr = N - 1;
                    const _Float16* gsrc = x16 + (size_t)gr * D + lane * 8;
                    __builtin_amdgcn_global_load_lds((const AS1 unsigned int*)gsrc,
                                                     (AS3 unsigned int*)(ybuf + r * 520), 16, 0, 0);
                }
            }
            if (kb >= 1) {
                const _Float16* pb = (const _Float16*)(smem + 98816 + par * 10240);
                f16x8 pa0 = *(const f16x8*)(pb + (qt * 2 + 0) * 640 + l15 * 40 + quad * 8);
                f16x8 pa1 = *(const f16x8*)(pb + (qt * 2 + 1) * 640 + l15 * 40 + quad * 8);
                const _Float16* zb = (const _Float16*)(smem + 33280 + par * 32768);
                __builtin_amdgcn_s_setprio(1);
                #pragma unroll
                for (int f = 8; f < 16; f++) {
                    f16x8 zf = *(const f16x8*)(zb + ((dg * 16 + f) * 16 + l15) * 32 + zcol);
                    big[0][f] = __builtin_amdgcn_mfma_f32_16x16x32_f16(pa0, zf, big[0][f], 0, 0, 0);
                    big[1][f] = __builtin_amdgcn_mfma_f32_16x16x32_f16(pa1, zf, big[1][f], 0, 0, 0);
                }
                __builtin_amdgcn_s_setprio(0);
            }
        } else if (kb < nkb) {
            // softmax + P/al write (defer-max THR=8)
            _Float16* pbw = (_Float16*)(smem + 98816 + (kb & 1) * 10240);
            float* alw = (float*)(smem + 119296 + (kb & 1) * 512);
            float* lbw = (float*)(smem + 120320);
            #pragma unroll
            for (int qs = 0; qs < 2; qs++) {
                const int g = sw * 2 + qs;
                #pragma unroll
                for (int r = 0; r < 4; r++) {
                    float t = fmaxf(s[qs][0][r], s[qs][1][r]);
                    t = fmaxf(t, __shfl_xor(t, 1, 16));
                    t = fmaxf(t, __shfl_xor(t, 2, 16));
                    t = fmaxf(t, __shfl_xor(t, 4, 16));
                    t = fmaxf(t, __shfl_xor(t, 8, 16));
                    bool upd = (t > mR[qs][r] + 8.0f);
                    float mn = upd ? t : mR[qs][r];
                    float al = upd ? __expf(mR[qs][r] - mn) : 1.0f;
                    mR[qs][r] = mn;
                    float e0 = __expf(s[qs][0][r] - mn);
                    float e1 = __expf(s[qs][1][r] - mn);
                    float ps = e0 + e1;
                    ps += __shfl_xor(ps, 1, 16);
                    ps += __shfl_xor(ps, 2, 16);
                    ps += __shfl_xor(ps, 4, 16);
                    ps += __shfl_xor(ps, 8, 16);
                    lR[qs][r] = lR[qs][r] * al + ps;
                    pbw[g * 640 + (quad * 4 + r) * 40 + l15]      = (_Float16)e0;
                    pbw[g * 640 + (quad * 4 + r) * 40 + 16 + l15] = (_Float16)e1;
                    if (l15 == 0) {
                        alw[g * 16 + quad * 4 + r] = al;
                        if (kb == nkb - 1) lbw[g * 16 + quad * 4 + r] = 1.0f / lR[qs][r];
                    }
                }
            }
        }

        __syncthreads();   // BAR2
    }

    // ---- epilogue: PV waves write out ----
    if (!isS) {
        const float* lbr = (const float*)(smem + 120320);
        f32x4 inv0 = *(const f32x4*)(lbr + (qt * 2 + 0) * 16 + quad * 4);
        f32x4 inv1 = *(const f32x4*)(lbr + (qt * 2 + 1) * 16 + quad * 4);
        #pragma unroll
        for (int qs = 0; qs < 2; qs++) {
            f32x4 inv = qs ? inv1 : inv0;
            #pragma unroll
            for (int r = 0; r < 4; r++) {
                int qloc = tile * 128 + qt * 32 + qs * 16 + quad * 4 + r;
                if (qloc < len) {
                    float* orow = out + (size_t)(off + qloc) * D + dg * 256 + l15;
                    #pragma unroll
                    for (int f = 0; f < 16; f++) orow[f * 16] = big[qs][f][r] * inv[r];
                }
            }
        }
    }
}

extern "C" void kernel_launch(void* const* d_in, const int* in_sizes, int n_in,
                              void* d_out, int out_size, void* d_ws, size_t ws_size,
                              hipStream_t stream) {
    const float* h    = (const float*)d_in[0];
    const float* W    = (const float*)d_in[1];
    const float* bias = (const float*)d_in[2];
    const int*   lens = (const int*)d_in[3];
    float* outp = (float*)d_out;

    const int N = in_sizes[0] / D;                 // 24064
    int B = in_sizes[3]; if (B > 16) B = 16;

    _Float16* x16 = (_Float16*)d_ws;                                  // N*D fp16
    _Float16* zTb = (_Float16*)((char*)d_ws + (size_t)N * D * 2);     // blocked+swizzled z^T

    dim3 g2(N / 64, D / 64);
    transpose_kernel<<<g2, 256, 0, stream>>>(h, zTb, N);

    dim3 g1(N / 128, D / 128);
    linear_mfma<<<g1, 256, 0, stream>>>(h, W, bias, x16, N);

    const int nblk = N / 128 + B;
    attn10_kernel<<<nblk, 768, 0, stream>>>(h, x16, zTb, lens, outp, N, B);
}